// Round 7
// baseline (391702.466 us; speedup 1.0000x reference)
//
#include <hip/hip_runtime.h>
#include <hip/hip_cooperative_groups.h>
#include <cstdint>
#include <cstddef>
#include <cstring>

// ---------------- problem constants ----------------
constexpr int TDEC   = 800;

// ---------------- workspace layout (floats/dwords) ----------------
constexpr int AH_OFF   = 0;               // 2 * 32*1024 (double-buffered)
constexpr int AC_OFF   = 65536;           // 32*1024
constexpr int DH_OFF   = 98304;           // 2 * 32*1024
constexpr int DC_OFF   = 163840;          // 32*1024
constexpr int CTX_OFF  = 196608;          // 2 * 32*512
constexpr int AW_OFF   = 229376;          // 32*256
constexpr int AWC_OFF  = 237568;          // 32*256
constexpr int BAR_OFF  = 245760;          // 256 u32 barrier slots
constexpr int STATE_FLOATS = 253952;      // memset region
constexpr int PRE_OFF  = 253952;          // 800*32*256
constexpr int PMEM_OFF = 6807552;         // 32*256*128
constexpr int W1T_OFF  = 7856128;         // 80*256
constexpr int W2T_OFF  = 7876608;         // 256*256
constexpr int LINT_OFF = 7942144;         // 128*32
constexpr int BLOB_OFF = 7946240;         // 256 * 34816 dwords (low-16 of weights)
constexpr int WCHUNKS_A = 14;             // attn chunks (1792/128)
constexpr int WCHUNKS_D = 20;             // dec chunks (2560/128)
constexpr int WBLK_DW  = 34816;           // (14+20)*1024 dwords per block

// LDS layout (bytes): [0,139264) hi-16 weights; [139264,160768) scratch (5376 floats)
constexpr int SCRATCH_F     = 5376;
constexpr int SMEM_BYTES    = 139264 + SCRATCH_F * 4;  // 160768 <= 163840

typedef __attribute__((ext_vector_type(4))) float f32x4;
typedef __attribute__((ext_vector_type(4))) unsigned int u32x4;

// ---------------- coherent (sc0 sc1) access helpers ----------------
__device__ __forceinline__ void coh_load4(const float* p, f32x4& v) {
  asm volatile("global_load_dwordx4 %0, %1, off sc0 sc1" : "=v"(v) : "v"(p));
}
__device__ __forceinline__ void coh_load1(const float* p, float& v) {
  asm volatile("global_load_dword %0, %1, off sc0 sc1" : "=v"(v) : "v"(p));
}
__device__ __forceinline__ void coh_store1(float* p, float v) {
  asm volatile("global_store_dword %0, %1, off sc0 sc1" :: "v"(p), "v"(v) : "memory");
}
__device__ __forceinline__ void coh_wait() {
  asm volatile("s_waitcnt vmcnt(0)" ::: "memory");
  __builtin_amdgcn_sched_barrier(0);
}

// flat all-read-all barrier: slot per block, monotone generation, no cache maintenance
__device__ __forceinline__ void gbar(uint32_t* slots, uint32_t val) {
  asm volatile("s_waitcnt vmcnt(0)" ::: "memory");
  __syncthreads();
  if (threadIdx.x == 0) {
    uint32_t* p = slots + blockIdx.x;
    asm volatile("global_store_dword %0, %1, off sc0 sc1" :: "v"(p), "v"(val) : "memory");
  }
  if (threadIdx.x < 64) {
    const uint32_t* sp = slots + threadIdx.x * 4;
    while (true) {
      u32x4 v4;
      asm volatile("global_load_dwordx4 %0, %1, off sc0 sc1" : "=v"(v4) : "v"(sp) : "memory");
      asm volatile("s_waitcnt vmcnt(0)" ::: "memory");
      if (v4.x >= val && v4.y >= val && v4.z >= val && v4.w >= val) break;
      __builtin_amdgcn_s_sleep(2);
    }
  }
  __syncthreads();
}

// ---------------- JAX threefry2x32 (exact) ----------------
__host__ __device__ inline void tf2x32(uint32_t k0, uint32_t k1, uint32_t& x0, uint32_t& x1) {
  const uint32_t ks2 = k0 ^ k1 ^ 0x1BD11BDAu;
  uint32_t y0 = x0 + k0, y1 = x1 + k1;
#define TFR(r) { y0 += y1; y1 = (y1 << (r)) | (y1 >> (32 - (r))); y1 ^= y0; }
  TFR(13) TFR(15) TFR(26) TFR(6)   y0 += k1;  y1 += ks2 + 1u;
  TFR(17) TFR(29) TFR(16) TFR(24)  y0 += ks2; y1 += k0 + 2u;
  TFR(13) TFR(15) TFR(26) TFR(6)   y0 += k0;  y1 += k1 + 3u;
  TFR(17) TFR(29) TFR(16) TFR(24)  y0 += k1;  y1 += ks2 + 4u;
  TFR(13) TFR(15) TFR(26) TFR(6)   y0 += ks2; y1 += k0 + 5u;
#undef TFR
  x0 = y0; x1 = y1;
}

__device__ inline bool tf_keep(uint32_t ka, uint32_t kb, uint32_t i) {
  uint32_t x0 = 0u, x1 = i;
  tf2x32(ka, kb, x0, x1);
  return (((x0 ^ x1) >> 31) == 0u);
}

__device__ inline float sigm(float x) { return 1.f / (1.f + expf(-x)); }

// weight (j,k) -> source pointer, shared by mklo kernel and scan prologue
__device__ __forceinline__ const float* wsrc(int c, int j, int kk,
                                             const float* aWih, const float* aWhh,
                                             const float* dWih, const float* dWhh) {
  if (c < WCHUNKS_A) {
    int k = c * 128 + kk;
    return (k < 768) ? (aWih + (size_t)j * 768 + k)
                     : (aWhh + (size_t)j * 1024 + (k - 768));
  } else {
    int k = (c - WCHUNKS_A) * 128 + kk;
    return (k < 1536) ? (dWih + (size_t)j * 1536 + k)
                      : (dWhh + (size_t)j * 1024 + (k - 1536));
  }
}

// ---------------- precompute kernels ----------------
__global__ __launch_bounds__(256) void transpose_k(const float* __restrict__ src,
                                                   float* __restrict__ dst, int R, int C) {
  int i = blockIdx.x * 256 + threadIdx.x;
  if (i < R * C) { int r = i / C, c = i % C; dst[c * R + r] = src[i]; }
}

__global__ __launch_bounds__(256) void prenet1_kernel(const float* __restrict__ decin,
                                                      const float* __restrict__ w1T,
                                                      float* __restrict__ pre,
                                                      uint32_t ka, uint32_t kb) {
  __shared__ float xs[32][81];
  const int t = blockIdx.x, tid = threadIdx.x;
  for (int f = tid; f < 32 * 80; f += 256) {
    int b = f / 80, m = f % 80;
    xs[b][m] = (t == 0) ? 0.f : decin[b * 64000 + m * 800 + (t - 1)];
  }
  __syncthreads();
  const int p = tid;
  float acc[32];
#pragma unroll
  for (int r = 0; r < 32; ++r) acc[r] = 0.f;
  for (int m = 0; m < 80; ++m) {
    float wv = w1T[m * 256 + p];
#pragma unroll
    for (int r = 0; r < 32; ++r) acc[r] += xs[r][m] * wv;
  }
  float* rowbase = pre + (size_t)t * 32 * 256;
#pragma unroll
  for (int r = 0; r < 32; ++r) {
    float v = fmaxf(acc[r], 0.f);
    uint32_t i = (uint32_t)((t * 32 + r) * 256 + p);
    rowbase[r * 256 + p] = tf_keep(ka, kb, i) ? v * 2.f : 0.f;
  }
}

__global__ __launch_bounds__(256) void prenet2_kernel(const float* __restrict__ w2T,
                                                      float* __restrict__ pre,
                                                      uint32_t ka, uint32_t kb) {
  __shared__ float hs[32][257];
  const int t = blockIdx.x, tid = threadIdx.x;
  float* rowbase = pre + (size_t)t * 32 * 256;
  for (int f = tid; f < 32 * 256; f += 256) {
    int b = f >> 8, k = f & 255;
    hs[b][k] = rowbase[b * 256 + k];
  }
  __syncthreads();
  const int p = tid;
  float acc[32];
#pragma unroll
  for (int r = 0; r < 32; ++r) acc[r] = 0.f;
  for (int k = 0; k < 256; ++k) {
    float wv = w2T[k * 256 + p];
#pragma unroll
    for (int r = 0; r < 32; ++r) acc[r] += hs[r][k] * wv;
  }
#pragma unroll
  for (int r = 0; r < 32; ++r) {
    float v = fmaxf(acc[r], 0.f);
    uint32_t i = (uint32_t)((t * 32 + r) * 256 + p);
    rowbase[r * 256 + p] = tf_keep(ka, kb, i) ? v * 2.f : 0.f;
  }
}

__global__ __launch_bounds__(128) void pmem_kernel(const float* __restrict__ enc,
                                                   const float* __restrict__ memW,
                                                   float* __restrict__ pmem) {
  __shared__ float es[8][513];
  const int b = blockIdx.x >> 5, tg = blockIdx.x & 31, t0 = tg * 8;
  const int tid = threadIdx.x;
  for (int f = tid; f < 8 * 512; f += 128) {
    int rr = f >> 9, e = f & 511;
    es[rr][e] = enc[(size_t)(b * 256 + t0 + rr) * 512 + e];
  }
  __syncthreads();
  float acc[8];
#pragma unroll
  for (int r = 0; r < 8; ++r) acc[r] = 0.f;
  const int a = tid;
  for (int e = 0; e < 512; ++e) {
    float wv = memW[e * 128 + a];
#pragma unroll
    for (int r = 0; r < 8; ++r) acc[r] += es[r][e] * wv;
  }
#pragma unroll
  for (int r = 0; r < 8; ++r) pmem[(size_t)(b * 256 + t0 + r) * 128 + a] = acc[r];
}

// build the low-16-bit blob in the same swizzled layout as the LDS hi-16 store
__global__ __launch_bounds__(1024) void mklo_kernel(const float* __restrict__ aWih,
                                                    const float* __restrict__ aWhh,
                                                    const float* __restrict__ dWih,
                                                    const float* __restrict__ dWhh,
                                                    uint32_t* __restrict__ blob) {
  __shared__ float tmp[2048];
  const int blk = blockIdx.x, tid = threadIdx.x;
  uint32_t* bdst = blob + (size_t)blk * WBLK_DW;
  for (int c = 0; c < WCHUNKS_A + WCHUNKS_D; ++c) {
    const int row16 = tid >> 6;
    const int kk = (tid & 63) * 2;
    const int j = (row16 >> 2) * 1024 + blk * 4 + (row16 & 3);
    float2 wv = *(const float2*)wsrc(c, j, kk, aWih, aWhh, dWih, dWhh);
    *(float2*)(tmp + row16 * 128 + kk) = wv;
    __syncthreads();
    const int rr = tid & 3, jgq = (tid >> 2) & 3, l = tid >> 4;
    uint32_t b0 = __float_as_uint(tmp[(jgq * 4 + rr) * 128 + l * 2]) & 0xffffu;
    uint32_t b1 = __float_as_uint(tmp[(jgq * 4 + rr) * 128 + l * 2 + 1]) & 0xffffu;
    bdst[c * 1024 + (l * 4 + jgq) * 4 + rr] = b0 | (b1 << 16);
    __syncthreads();
  }
}

// ---------------- scan (persistent, LDS hi-16 + global lo-16 = exact fp32) ----------------
struct ScanParams {
  const float* enc; const int* lens;
  const float* aWih; const float* aWhh; const float* abih; const float* abhh;
  const float* qW;   const float* vw;   const float* locW; const float* linT;
  const float* dWih; const float* dWhh; const float* dbih; const float* dbhh;
  const float* pW;   const float* pb;   const float* gW;   const float* gb;
  float* ah; float* ac; float* dh; float* dc; float* ctx; float* aw; float* awc;
  uint32_t* bar; const uint32_t* wlo;
  const float* pre; const float* pmem;
  float* mel_out; float* gate_out; float* align_out;
};

struct XW { const float* x; int ldx; int coh; };

// block: 1024 threads = jg(4 gates) x bg(4) x lane(64). Per-thread tile: 4 rows x 8 b.
// Weights: hi-16 in LDS + lo-16 from global blob, merged to exact fp32.
// Chunk layout [l=64][jg=4][rr=4][k2=2] (4 KB per 128-k chunk, both halves).
template <typename F>
__device__ __forceinline__ void lstm_lds(int blk, int tid, int nc, F getx,
                                         const uint32_t* wch0, const uint32_t* lch0,
                                         const float* bih, const float* bhh,
                                         float* hout, float* cst,
                                         float* xs, float* gate_s) {
  const int lane = tid & 63;
  const int bg = (tid >> 6) & 3;
  const int jg = tid >> 8;            // gate index 0..3 (i,f,g,o)
  const int b0 = bg * 8;
  const int hb = blk << 2;
  const int woff = (lane * 4 + jg) << 2;

  float acc[4][8];
#pragma unroll
  for (int rr = 0; rr < 4; ++rr) {
    float bv = (lane == 0) ? (bih[jg * 1024 + hb + rr] + bhh[jg * 1024 + hb + rr]) : 0.f;
#pragma unroll
    for (int bb = 0; bb < 8; ++bb) acc[rr][bb] = bv;
  }

  const int sb = tid >> 5;            // staging batch row
  const int skq = (tid & 31) * 4;     // staging k within chunk
  f32x4 sreg;
  u32x4 lcur, lnxt;
  {
    XW x0 = getx(0);
    const float* p = x0.x + (size_t)sb * x0.ldx + skq;
    lcur = *(const u32x4*)(lch0 + woff);          // lo-16 chunk 0
    if (x0.coh) { coh_load4(p, sreg); coh_wait(); }
    else        sreg = *(const f32x4*)p;
    *(f32x4*)(xs + sb * 132 + skq) = sreg;
  }
  __syncthreads();

  for (int c = 0; c < nc; ++c) {
    const bool more = (c + 1 < nc);
    if (more) {
      XW xn = getx(c + 1);
      const float* p = xn.x + (size_t)sb * xn.ldx + skq;
      lnxt = *(const u32x4*)(lch0 + (c + 1) * 1024 + woff);
      if (xn.coh) coh_load4(p, sreg);
      else        sreg = *(const f32x4*)p;
    }
    u32x4 wv = *(const u32x4*)(wch0 + c * 1024 + woff);
    float we[4], wo[4];
#pragma unroll
    for (int rr = 0; rr < 4; ++rr) {
      uint32_t h = wv[rr], l = lcur[rr];
      we[rr] = __uint_as_float((h << 16) | (l & 0xffffu));          // k even: exact fp32
      wo[rr] = __uint_as_float((h & 0xffff0000u) | (l >> 16));      // k odd:  exact fp32
    }
#pragma unroll
    for (int bb = 0; bb < 8; ++bb) {
      float2 x2 = *(const float2*)(xs + (b0 + bb) * 132 + lane * 2);
#pragma unroll
      for (int rr = 0; rr < 4; ++rr)
        acc[rr][bb] = fmaf(wo[rr], x2.y, fmaf(we[rr], x2.x, acc[rr][bb]));
    }
    __syncthreads();                   // everyone done reading xs
    if (more) {
      coh_wait();                      // sreg (and lnxt) arrived
      *(f32x4*)(xs + sb * 132 + skq) = sreg;
      lcur = lnxt;
      __syncthreads();
    }
  }

  // reduce 32 partials across 64 lanes: halving butterfly
  float v[32];
#pragma unroll
  for (int rr = 0; rr < 4; ++rr)
#pragma unroll
    for (int bb = 0; bb < 8; ++bb) v[rr * 8 + bb] = acc[rr][bb];
#pragma unroll
  for (int s = 0; s < 5; ++s) {
    const int d = 32 >> s;
    const int half = 32 >> (s + 1);
    const bool up = (lane & d) != 0;
#pragma unroll
    for (int i = 0; i < 16; ++i) {
      if (i < half) {
        float send = up ? v[i] : v[i + half];
        float got = __shfl_xor(send, d);
        v[i] = (up ? v[i + half] : v[i]) + got;
      }
    }
  }
  v[0] += __shfl_xor(v[0], 1);
  if ((lane & 1) == 0) {
    int p = (lane >> 1) & 31;
    int rr = p >> 3, bb = p & 7;
    gate_s[(jg * 4 + rr) * 33 + (b0 + bb)] = v[0];
  }
  __syncthreads();
  if (tid < 128) {
    int hl = tid >> 5, b = tid & 31;
    float gi = gate_s[(0 + hl) * 33 + b];
    float gf = gate_s[(4 + hl) * 33 + b];
    float gg = gate_s[(8 + hl) * 33 + b];
    float go = gate_s[(12 + hl) * 33 + b];
    int idx = b * 1024 + hb + hl;
    float c0v = cst[idx];
    float cn = sigm(gf) * c0v + sigm(gi) * tanhf(gg);
    cst[idx] = cn;
    coh_store1(hout + idx, sigm(go) * tanhf(cn));
  }
  __syncthreads();
}

// fused attention for batch b (one block per b); scratch S = 5376 floats
__device__ void stage_attn(int b, int tid, int t, const ScanParams& P,
                           const float* ah_cur, float* ctx_out, float* S) {
  float* ah_l = S;           // 1024 (phase A only)
  float* part = S + 1024;    // 1024 (phase A only)
  float* lf   = S;           // 128*33 = 4224 (conv/energy; overlaps ah_l/part)
  float* sLoc = S + 4224;    // 572
  float* q_s  = S + 4800;    // 128
  float* vw_s = S + 4928;    // 128
  float* red  = S + 5056;    // 8
  float* aw_s = S + 5064;    // 256
  float* cpart= S + 1024;    // 1024 (phase E; lf dead by then)

  float ahv;
  coh_load1(ah_cur + b * 1024 + tid, ahv);
  if (tid < 572) {
    int c = tid / 286, i = tid % 286;
    int src = i - 15;
    float vv = 0.f;
    if (src >= 0 && src < 256) vv = (c == 0 ? P.aw : P.awc)[b * 256 + src];
    sLoc[c * 286 + i] = vv;
  } else if (tid < 700) {
    vw_s[tid - 572] = P.vw[tid - 572];
  }
  coh_wait();
  ah_l[tid] = ahv;
  __syncthreads();
  // phase A: q partials
  {
    const int js = tid >> 7, a = tid & 127;
    const float* ahb = ah_l + js * 128;
    const float* qp = P.qW + (size_t)(js * 128) * 128 + a;
    float p0 = 0.f, p1 = 0.f, p2 = 0.f, p3 = 0.f;
    for (int j = 0; j < 128; j += 4) {
      p0 += ahb[j] * qp[(size_t)j * 128];
      p1 += ahb[j + 1] * qp[(size_t)(j + 1) * 128];
      p2 += ahb[j + 2] * qp[(size_t)(j + 2) * 128];
      p3 += ahb[j + 3] * qp[(size_t)(j + 3) * 128];
    }
    part[tid] = (p0 + p1) + (p2 + p3);
  }
  __syncthreads();
  if (tid < 128) {
    float q = 0.f;
#pragma unroll
    for (int js = 0; js < 8; ++js) q += part[js * 128 + tid];
    q_s[tid] = q;
  }
  __syncthreads();   // part/ah_l dead; lf region free
  const int len_b = P.lens[b];
#pragma unroll 1
  for (int h = 0; h < 2; ++h) {
    const int tt0 = h << 7;
    {  // location conv for tt in [tt0, tt0+128): thread = f(32) x seg(32), 4 tt each
      const int f = tid >> 5, seg = tid & 31;
      float a0 = 0.f, a1 = 0.f, a2 = 0.f, a3 = 0.f;
      const float* wf = P.locW + f * 62;
#pragma unroll
      for (int c2 = 0; c2 < 2; ++c2)
#pragma unroll
        for (int k = 0; k < 31; ++k) {
          float wv = wf[c2 * 31 + k];
          const float* sl = sLoc + c2 * 286 + tt0 + seg * 4 + k;
          a0 = fmaf(sl[0], wv, a0); a1 = fmaf(sl[1], wv, a1);
          a2 = fmaf(sl[2], wv, a2); a3 = fmaf(sl[3], wv, a3);
        }
      lf[(seg * 4 + 0) * 33 + f] = a0; lf[(seg * 4 + 1) * 33 + f] = a1;
      lf[(seg * 4 + 2) * 33 + f] = a2; lf[(seg * 4 + 3) * 33 + f] = a3;
    }
    __syncthreads();
    {  // energies: thread = ttl(128) x aq(8)
      const int ttl = tid >> 3, aq = tid & 7;
      const int tt = tt0 + ttl;
      const float* pm = P.pmem + (size_t)(b * 256 + tt) * 128;
      const float* lfr = lf + ttl * 33;
      float lfv[32];
#pragma unroll
      for (int f = 0; f < 32; ++f) lfv[f] = lfr[f];
      float ep = 0.f;
#pragma unroll 2
      for (int ai = 0; ai < 16; ++ai) {
        int a = aq * 16 + ai;
        const float4* lt = (const float4*)(P.linT + a * 32);
        float lfa = 0.f;
#pragma unroll
        for (int u = 0; u < 8; ++u) {
          float4 l4 = lt[u];
          lfa += l4.x * lfv[u * 4] + l4.y * lfv[u * 4 + 1] + l4.z * lfv[u * 4 + 2] + l4.w * lfv[u * 4 + 3];
        }
        ep += vw_s[a] * tanhf(q_s[a] + lfa + pm[a]);
      }
      ep += __shfl_xor(ep, 1); ep += __shfl_xor(ep, 2); ep += __shfl_xor(ep, 4);
      if (aq == 0) aw_s[tt] = (tt < len_b) ? ep : -1e9f;
    }
    __syncthreads();
  }
  // softmax over aw_s (in place)
  if (tid < 64) {
    float m0 = fmaxf(fmaxf(aw_s[tid], aw_s[64 + tid]), fmaxf(aw_s[128 + tid], aw_s[192 + tid]));
#pragma unroll
    for (int m = 32; m >= 1; m >>= 1) m0 = fmaxf(m0, __shfl_xor(m0, m));
    if (tid == 0) red[0] = m0;
  }
  __syncthreads();
  const float mx = red[0];
  if (tid < 256) aw_s[tid] = expf(aw_s[tid] - mx);
  __syncthreads();
  if (tid < 64) {
    float s0 = aw_s[tid] + aw_s[64 + tid] + aw_s[128 + tid] + aw_s[192 + tid];
#pragma unroll
    for (int m = 32; m >= 1; m >>= 1) s0 += __shfl_xor(s0, m);
    if (tid == 0) red[1] = s0;
  }
  __syncthreads();
  const float inv = 1.f / red[1];
  if (tid < 256) {
    float awv = aw_s[tid] * inv;
    aw_s[tid] = awv;
    P.aw[b * 256 + tid] = awv;
    P.awc[b * 256 + tid] += awv;
    P.align_out[(size_t)b * 204800 + (size_t)t * 256 + tid] = awv;
  }
  __syncthreads();
  // phase E: ctx = aw @ enc (enc L2-warm, normal loads)
  {
    const int ee = tid & 511, hf = tid >> 9;
    const float* encb = P.enc + (size_t)b * 131072 + (size_t)hf * 128 * 512 + ee;
    float a0 = 0.f, a1 = 0.f, a2 = 0.f, a3 = 0.f;
    for (int tt = 0; tt < 128; tt += 4) {
      a0 += aw_s[hf * 128 + tt] * encb[(size_t)tt * 512];
      a1 += aw_s[hf * 128 + tt + 1] * encb[(size_t)(tt + 1) * 512];
      a2 += aw_s[hf * 128 + tt + 2] * encb[(size_t)(tt + 2) * 512];
      a3 += aw_s[hf * 128 + tt + 3] * encb[(size_t)(tt + 3) * 512];
    }
    cpart[hf * 512 + ee] = (a0 + a1) + (a2 + a3);
  }
  __syncthreads();
  if (tid < 512) coh_store1(ctx_out + b * 512 + tid, cpart[tid] + cpart[512 + tid]);
}

__device__ void stage_proj(int b, int tid, int tp, const ScanParams& P,
                           const float* dh_prev, const float* ctx_prev, float* S) {
  float* hc    = S;         // 1536
  float* partm = S + 1536;  // 480
  float* partg = S + 2016;  // 32
  for (int i = tid; i < 1536; i += 1024) {
    float v;
    const float* p = (i < 1024) ? (dh_prev + b * 1024 + i) : (ctx_prev + b * 512 + (i - 1024));
    coh_load1(p, v);
    coh_wait();
    hc[i] = v;
  }
  __syncthreads();
  if (tid < 480) {
    int ks = tid / 80, m = tid % 80;
    const float* pWk = P.pW + (size_t)(ks * 256) * 80 + m;
    const float* hck = hc + ks * 256;
    float a0 = 0.f, a1 = 0.f, a2 = 0.f, a3 = 0.f;
    for (int k = 0; k < 256; k += 4) {
      a0 += hck[k] * pWk[(size_t)k * 80];
      a1 += hck[k + 1] * pWk[(size_t)(k + 1) * 80];
      a2 += hck[k + 2] * pWk[(size_t)(k + 2) * 80];
      a3 += hck[k + 3] * pWk[(size_t)(k + 3) * 80];
    }
    partm[ks * 80 + m] = (a0 + a1) + (a2 + a3);
  } else if (tid < 512) {
    int s = tid - 480;
    float acc = 0.f;
    for (int k = s * 48; k < s * 48 + 48; ++k) acc += hc[k] * P.gW[k];
    partg[s] = acc;
  }
  __syncthreads();
  if (tid < 80) {
    float acc = P.pb[tid];
#pragma unroll
    for (int s = 0; s < 6; ++s) acc += partm[s * 80 + tid];
    P.mel_out[b * 64000 + tid * 800 + tp] = acc;
  }
  if (tid == 511) {
    float acc = P.gb[0];
#pragma unroll
    for (int s = 0; s < 32; ++s) acc += partg[s];
    P.gate_out[b * 800 + tp] = acc;
  }
  __syncthreads();
}

__global__ void __launch_bounds__(1024, 4) scan_kernel(ScanParams P) {
  extern __shared__ char dynsmem[];
  uint32_t* wlds = (uint32_t*)dynsmem;                       // 34816 dwords (hi-16)
  float* scratch = (float*)(dynsmem + 139264);               // 5376 floats
  float* xs = scratch;                                       // 4224
  float* gate_s = scratch + 4224;                            // 528
  const int blk = blockIdx.x, tid = threadIdx.x;

  // ---- prologue: gather this block's weight slice -> LDS hi-16 (truncated, swizzled) ----
  {
    float* tmp = xs;                                         // 16*128 = 2048 floats
    for (int c = 0; c < WCHUNKS_A + WCHUNKS_D; ++c) {
      const int row16 = tid >> 6;
      const int kk = (tid & 63) * 2;
      const int j = (row16 >> 2) * 1024 + blk * 4 + (row16 & 3);
      float2 wv = *(const float2*)wsrc(c, j, kk, P.aWih, P.aWhh, P.dWih, P.dWhh);
      *(float2*)(tmp + row16 * 128 + kk) = wv;
      __syncthreads();
      const int rr = tid & 3, jgq = (tid >> 2) & 3, l = tid >> 4;
      uint32_t hi0 = __float_as_uint(tmp[(jgq * 4 + rr) * 128 + l * 2]) >> 16;
      uint32_t hi1 = __float_as_uint(tmp[(jgq * 4 + rr) * 128 + l * 2 + 1]) >> 16;
      wlds[c * 1024 + (l * 4 + jgq) * 4 + rr] = hi0 | (hi1 << 16);
      __syncthreads();
    }
  }
  __syncthreads();

  const uint32_t* lblk = P.wlo + (size_t)blk * WBLK_DW;
  uint32_t* slots = P.bar;
  uint32_t bk = 0;

  for (int i = 0; i <= TDEC; ++i) {
    const int pi = i & 1, pim1 = pi ^ 1;
    // ---- stage X: attn-LSTM(i) then dec-LSTM(i-1) ----
    if (i < TDEC) {
      const float* pre_t = P.pre + (size_t)i * 8192;
      const float* ctx_r = P.ctx + pim1 * 16384;
      const float* ah_r  = P.ah + pim1 * 32768;
      auto getxA = [&](int c) -> XW {
        XW r;
        if (c < 2)      { r.x = pre_t + c * 128;        r.ldx = 256;  r.coh = 0; }
        else if (c < 6) { r.x = ctx_r + (c - 2) * 128;  r.ldx = 512;  r.coh = 1; }
        else            { r.x = ah_r + (c - 6) * 128;   r.ldx = 1024; r.coh = 1; }
        return r;
      };
      lstm_lds(blk, tid, WCHUNKS_A, getxA, wlds, lblk, P.abih, P.abhh,
               P.ah + pi * 32768, P.ac, xs, gate_s);
    }
    if (i >= 1) {
      const float* ah_w  = P.ah + pim1 * 32768;    // ah(i-1)
      const float* ctx_w = P.ctx + pim1 * 16384;   // ctx(i-1)
      const float* dh_r  = P.dh + pi * 32768;      // dh(i-2)
      auto getxD = [&](int c) -> XW {
        XW r;
        if (c < 8)       { r.x = ah_w + c * 128;         r.ldx = 1024; r.coh = 1; }
        else if (c < 12) { r.x = ctx_w + (c - 8) * 128;  r.ldx = 512;  r.coh = 1; }
        else             { r.x = dh_r + (c - 12) * 128;  r.ldx = 1024; r.coh = 1; }
        return r;
      };
      lstm_lds(blk, tid, WCHUNKS_D, getxD, wlds + WCHUNKS_A * 1024,
               lblk + WCHUNKS_A * 1024, P.dbih, P.dbhh,
               P.dh + pim1 * 32768, P.dc, xs, gate_s);
    }
    gbar(slots, ++bk);
    // ---- stage Y: attention(i) || proj(i-1) ----
    if (blk < 32) {
      if (i < TDEC) stage_attn(blk, tid, i, P, P.ah + pi * 32768, P.ctx + pi * 16384, scratch);
    } else if (blk < 64) {
      if (i >= 1) stage_proj(blk - 32, tid, i - 1, P, P.dh + pim1 * 32768, P.ctx + pim1 * 16384, scratch);
    }
    gbar(slots, ++bk);
  }
}

// ---------------- host launch ----------------
extern "C" void kernel_launch(void* const* d_in, const int* in_sizes, int n_in,
                              void* d_out, int out_size, void* d_ws, size_t ws_size,
                              hipStream_t stream) {
  (void)in_sizes; (void)n_in; (void)out_size; (void)ws_size;
  const float* enc   = (const float*)d_in[0];
  const float* decin = (const float*)d_in[1];
  const int*   lens  = (const int*)d_in[2];
  const float* w1    = (const float*)d_in[3];
  const float* w2    = (const float*)d_in[4];
  const float* aWih  = (const float*)d_in[5];
  const float* aWhh  = (const float*)d_in[6];
  const float* abih  = (const float*)d_in[7];
  const float* abhh  = (const float*)d_in[8];
  const float* qW    = (const float*)d_in[9];
  const float* memW  = (const float*)d_in[10];
  const float* vw    = (const float*)d_in[11];
  const float* locW  = (const float*)d_in[12];
  const float* linW  = (const float*)d_in[13];
  const float* dWih  = (const float*)d_in[14];
  const float* dWhh  = (const float*)d_in[15];
  const float* dbih  = (const float*)d_in[16];
  const float* dbhh  = (const float*)d_in[17];
  const float* pW    = (const float*)d_in[18];
  const float* pb    = (const float*)d_in[19];
  const float* gW    = (const float*)d_in[20];
  const float* gb    = (const float*)d_in[21];

  float* ws  = (float*)d_ws;
  float* out = (float*)d_out;

  (void)hipMemsetAsync(ws, 0, (size_t)STATE_FLOATS * sizeof(float), stream);

  uint32_t k1a, k1b, k2a, k2b;
  { uint32_t a = 0u, b = 0u; tf2x32(0u, 42u, a, b); k1a = a; k1b = b; }
  { uint32_t a = 0u, b = 1u; tf2x32(0u, 42u, a, b); k2a = a; k2b = b; }

  transpose_k<<<dim3((256 * 80 + 255) / 256), dim3(256), 0, stream>>>(w1, ws + W1T_OFF, 256, 80);
  transpose_k<<<dim3((256 * 256 + 255) / 256), dim3(256), 0, stream>>>(w2, ws + W2T_OFF, 256, 256);
  transpose_k<<<dim3((32 * 128 + 255) / 256), dim3(256), 0, stream>>>(linW, ws + LINT_OFF, 32, 128);
  prenet1_kernel<<<dim3(800), dim3(256), 0, stream>>>(decin, ws + W1T_OFF, ws + PRE_OFF, k1a, k1b);
  prenet2_kernel<<<dim3(800), dim3(256), 0, stream>>>(ws + W2T_OFF, ws + PRE_OFF, k2a, k2b);
  pmem_kernel<<<dim3(1024), dim3(128), 0, stream>>>(enc, memW, ws + PMEM_OFF);
  mklo_kernel<<<dim3(256), dim3(1024), 0, stream>>>(aWih, aWhh, dWih, dWhh,
                                                    (uint32_t*)(ws + BLOB_OFF));

  ScanParams prm;
  prm.enc = enc; prm.lens = lens;
  prm.aWih = aWih; prm.aWhh = aWhh; prm.abih = abih; prm.abhh = abhh;
  prm.qW = qW; prm.vw = vw; prm.locW = locW; prm.linT = ws + LINT_OFF;
  prm.dWih = dWih; prm.dWhh = dWhh; prm.dbih = dbih; prm.dbhh = dbhh;
  prm.pW = pW; prm.pb = pb; prm.gW = gW; prm.gb = gb;
  prm.ah = ws + AH_OFF; prm.ac = ws + AC_OFF;
  prm.dh = ws + DH_OFF; prm.dc = ws + DC_OFF;
  prm.ctx = ws + CTX_OFF; prm.aw = ws + AW_OFF; prm.awc = ws + AWC_OFF;
  prm.bar = (uint32_t*)(ws + BAR_OFF);
  prm.wlo = (const uint32_t*)(ws + BLOB_OFF);
  prm.pre = ws + PRE_OFF; prm.pmem = ws + PMEM_OFF;
  prm.mel_out = out; prm.gate_out = out + 2048000; prm.align_out = out + 2073600;

  (void)hipFuncSetAttribute((const void*)scan_kernel,
                            hipFuncAttributeMaxDynamicSharedMemorySize, SMEM_BYTES);

  void* kargs[] = { (void*)&prm };
  (void)hipLaunchCooperativeKernel(scan_kernel, dim3(256), dim3(1024), kargs, SMEM_BYTES, stream);
}

// Round 8
// 374118.774 us; speedup vs baseline: 1.0470x; 1.0470x over previous
//
#include <hip/hip_runtime.h>
#include <hip/hip_cooperative_groups.h>
#include <cstdint>
#include <cstddef>
#include <cstring>

// ---------------- problem constants ----------------
constexpr int TDEC   = 800;

// ---------------- workspace layout (floats/dwords) ----------------
constexpr int AH_OFF   = 0;               // 2 * 32*1024 (double-buffered)
constexpr int AC_OFF   = 65536;           // 32*1024
constexpr int DH_OFF   = 98304;           // 2 * 32*1024
constexpr int DC_OFF   = 163840;          // 32*1024
constexpr int CTX_OFF  = 196608;          // 2 * 32*512
constexpr int AW_OFF   = 229376;          // 32*256
constexpr int AWC_OFF  = 237568;          // 32*256
constexpr int BAR_OFF  = 245760;          // 256 u32 barrier slots
constexpr int STATE_FLOATS = 253952;      // memset region
constexpr int PRE_OFF  = 253952;          // 800*32*256
constexpr int PMEM_OFF = 6807552;         // 32*256*128
constexpr int W1T_OFF  = 7856128;         // 80*256
constexpr int W2T_OFF  = 7876608;         // 256*256
constexpr int LINT_OFF = 7942144;         // 128*32
constexpr int BLOB_OFF = 7946240;         // 256 * 34816 dwords (low-16 of weights)
constexpr int WCHUNKS_A = 14;             // attn chunks (1792/128)
constexpr int WCHUNKS_D = 20;             // dec chunks (2560/128)
constexpr int WBLK_DW  = 34816;           // (14+20)*1024 dwords per block

// LDS layout (bytes): [0,139264) hi-16 weights; [139264,160768) scratch (5376 floats)
constexpr int SCRATCH_F     = 5376;
constexpr int SMEM_BYTES    = 139264 + SCRATCH_F * 4;  // 160768 <= 163840

typedef __attribute__((ext_vector_type(4))) float f32x4;
typedef __attribute__((ext_vector_type(4))) unsigned int u32x4;

// ---------------- write-through (sc0 sc1) store helpers ----------------
__device__ __forceinline__ void coh_store1(float* p, float v) {
  asm volatile("global_store_dword %0, %1, off sc0 sc1" :: "v"(p), "v"(v) : "memory");
}

// flat all-read-all barrier + agent-acquire fence (L1/L2 invalidate, no writeback
// needed because all scan-loop stores are write-through)
__device__ __forceinline__ void gbar(uint32_t* slots, uint32_t val) {
  asm volatile("s_waitcnt vmcnt(0)" ::: "memory");   // drain write-through stores
  __syncthreads();
  if (threadIdx.x == 0) {
    uint32_t* p = slots + blockIdx.x;
    asm volatile("global_store_dword %0, %1, off sc0 sc1" :: "v"(p), "v"(val) : "memory");
  }
  if (threadIdx.x < 64) {
    const uint32_t* sp = slots + threadIdx.x * 4;
    while (true) {
      u32x4 v4;
      asm volatile("global_load_dwordx4 %0, %1, off sc0 sc1" : "=v"(v4) : "v"(sp) : "memory");
      asm volatile("s_waitcnt vmcnt(0)" ::: "memory");
      if (v4.x >= val && v4.y >= val && v4.z >= val && v4.w >= val) break;
      __builtin_amdgcn_s_sleep(2);
    }
  }
  __syncthreads();
  __builtin_amdgcn_fence(__ATOMIC_ACQUIRE, "agent");  // buffer_inv: fresh L2 view
}

// ---------------- JAX threefry2x32 (exact) ----------------
__host__ __device__ inline void tf2x32(uint32_t k0, uint32_t k1, uint32_t& x0, uint32_t& x1) {
  const uint32_t ks2 = k0 ^ k1 ^ 0x1BD11BDAu;
  uint32_t y0 = x0 + k0, y1 = x1 + k1;
#define TFR(r) { y0 += y1; y1 = (y1 << (r)) | (y1 >> (32 - (r))); y1 ^= y0; }
  TFR(13) TFR(15) TFR(26) TFR(6)   y0 += k1;  y1 += ks2 + 1u;
  TFR(17) TFR(29) TFR(16) TFR(24)  y0 += ks2; y1 += k0 + 2u;
  TFR(13) TFR(15) TFR(26) TFR(6)   y0 += k0;  y1 += k1 + 3u;
  TFR(17) TFR(29) TFR(16) TFR(24)  y0 += k1;  y1 += ks2 + 4u;
  TFR(13) TFR(15) TFR(26) TFR(6)   y0 += ks2; y1 += k0 + 5u;
#undef TFR
  x0 = y0; x1 = y1;
}

__device__ inline bool tf_keep(uint32_t ka, uint32_t kb, uint32_t i) {
  uint32_t x0 = 0u, x1 = i;
  tf2x32(ka, kb, x0, x1);
  return (((x0 ^ x1) >> 31) == 0u);
}

__device__ inline float sigm(float x) { return 1.f / (1.f + expf(-x)); }

// weight (j,k) -> source pointer, shared by mklo kernel and scan prologue
__device__ __forceinline__ const float* wsrc(int c, int j, int kk,
                                             const float* aWih, const float* aWhh,
                                             const float* dWih, const float* dWhh) {
  if (c < WCHUNKS_A) {
    int k = c * 128 + kk;
    return (k < 768) ? (aWih + (size_t)j * 768 + k)
                     : (aWhh + (size_t)j * 1024 + (k - 768));
  } else {
    int k = (c - WCHUNKS_A) * 128 + kk;
    return (k < 1536) ? (dWih + (size_t)j * 1536 + k)
                      : (dWhh + (size_t)j * 1024 + (k - 1536));
  }
}

// ---------------- precompute kernels ----------------
__global__ __launch_bounds__(256) void transpose_k(const float* __restrict__ src,
                                                   float* __restrict__ dst, int R, int C) {
  int i = blockIdx.x * 256 + threadIdx.x;
  if (i < R * C) { int r = i / C, c = i % C; dst[c * R + r] = src[i]; }
}

__global__ __launch_bounds__(256) void prenet1_kernel(const float* __restrict__ decin,
                                                      const float* __restrict__ w1T,
                                                      float* __restrict__ pre,
                                                      uint32_t ka, uint32_t kb) {
  __shared__ float xs[32][81];
  const int t = blockIdx.x, tid = threadIdx.x;
  for (int f = tid; f < 32 * 80; f += 256) {
    int b = f / 80, m = f % 80;
    xs[b][m] = (t == 0) ? 0.f : decin[b * 64000 + m * 800 + (t - 1)];
  }
  __syncthreads();
  const int p = tid;
  float acc[32];
#pragma unroll
  for (int r = 0; r < 32; ++r) acc[r] = 0.f;
  for (int m = 0; m < 80; ++m) {
    float wv = w1T[m * 256 + p];
#pragma unroll
    for (int r = 0; r < 32; ++r) acc[r] += xs[r][m] * wv;
  }
  float* rowbase = pre + (size_t)t * 32 * 256;
#pragma unroll
  for (int r = 0; r < 32; ++r) {
    float v = fmaxf(acc[r], 0.f);
    uint32_t i = (uint32_t)((t * 32 + r) * 256 + p);
    rowbase[r * 256 + p] = tf_keep(ka, kb, i) ? v * 2.f : 0.f;
  }
}

__global__ __launch_bounds__(256) void prenet2_kernel(const float* __restrict__ w2T,
                                                      float* __restrict__ pre,
                                                      uint32_t ka, uint32_t kb) {
  __shared__ float hs[32][257];
  const int t = blockIdx.x, tid = threadIdx.x;
  float* rowbase = pre + (size_t)t * 32 * 256;
  for (int f = tid; f < 32 * 256; f += 256) {
    int b = f >> 8, k = f & 255;
    hs[b][k] = rowbase[b * 256 + k];
  }
  __syncthreads();
  const int p = tid;
  float acc[32];
#pragma unroll
  for (int r = 0; r < 32; ++r) acc[r] = 0.f;
  for (int k = 0; k < 256; ++k) {
    float wv = w2T[k * 256 + p];
#pragma unroll
    for (int r = 0; r < 32; ++r) acc[r] += hs[r][k] * wv;
  }
#pragma unroll
  for (int r = 0; r < 32; ++r) {
    float v = fmaxf(acc[r], 0.f);
    uint32_t i = (uint32_t)((t * 32 + r) * 256 + p);
    rowbase[r * 256 + p] = tf_keep(ka, kb, i) ? v * 2.f : 0.f;
  }
}

__global__ __launch_bounds__(128) void pmem_kernel(const float* __restrict__ enc,
                                                   const float* __restrict__ memW,
                                                   float* __restrict__ pmem) {
  __shared__ float es[8][513];
  const int b = blockIdx.x >> 5, tg = blockIdx.x & 31, t0 = tg * 8;
  const int tid = threadIdx.x;
  for (int f = tid; f < 8 * 512; f += 128) {
    int rr = f >> 9, e = f & 511;
    es[rr][e] = enc[(size_t)(b * 256 + t0 + rr) * 512 + e];
  }
  __syncthreads();
  float acc[8];
#pragma unroll
  for (int r = 0; r < 8; ++r) acc[r] = 0.f;
  const int a = tid;
  for (int e = 0; e < 512; ++e) {
    float wv = memW[e * 128 + a];
#pragma unroll
    for (int r = 0; r < 8; ++r) acc[r] += es[r][e] * wv;
  }
#pragma unroll
  for (int r = 0; r < 8; ++r) pmem[(size_t)(b * 256 + t0 + r) * 128 + a] = acc[r];
}

// build the low-16-bit blob in the same layout as the LDS hi-16 store:
// dword index = c*1024 + jg*256 + l*4 + rr
__global__ __launch_bounds__(1024) void mklo_kernel(const float* __restrict__ aWih,
                                                    const float* __restrict__ aWhh,
                                                    const float* __restrict__ dWih,
                                                    const float* __restrict__ dWhh,
                                                    uint32_t* __restrict__ blob) {
  __shared__ float tmp[2048];
  const int blk = blockIdx.x, tid = threadIdx.x;
  uint32_t* bdst = blob + (size_t)blk * WBLK_DW;
  for (int c = 0; c < WCHUNKS_A + WCHUNKS_D; ++c) {
    const int row16 = tid >> 6;
    const int kk = (tid & 63) * 2;
    const int j = (row16 >> 2) * 1024 + blk * 4 + (row16 & 3);
    float2 wv = *(const float2*)wsrc(c, j, kk, aWih, aWhh, dWih, dWhh);
    *(float2*)(tmp + row16 * 128 + kk) = wv;
    __syncthreads();
    const int rr = tid & 3, jgq = (tid >> 2) & 3, l = tid >> 4;
    uint32_t b0 = __float_as_uint(tmp[(jgq * 4 + rr) * 128 + l * 2]) & 0xffffu;
    uint32_t b1 = __float_as_uint(tmp[(jgq * 4 + rr) * 128 + l * 2 + 1]) & 0xffffu;
    bdst[c * 1024 + jgq * 256 + l * 4 + rr] = b0 | (b1 << 16);
    __syncthreads();
  }
}

// ---------------- scan (persistent, LDS hi-16 + global lo-16 = exact fp32) ----------------
struct ScanParams {
  const float* enc; const int* lens;
  const float* aWih; const float* aWhh; const float* abih; const float* abhh;
  const float* qW;   const float* vw;   const float* locW; const float* linT;
  const float* dWih; const float* dWhh; const float* dbih; const float* dbhh;
  const float* pW;   const float* pb;   const float* gW;   const float* gb;
  float* ah; float* ac; float* dh; float* dc; float* ctx; float* aw; float* awc;
  uint32_t* bar; const uint32_t* wlo;
  const float* pre; const float* pmem;
  float* mel_out; float* gate_out; float* align_out;
};

struct XW { const float* x; int ldx; };

// block: 1024 threads = jg(4 gates) x bg(4) x lane(64). Per-thread tile: 4 rows x 8 b.
// Weights: hi-16 in LDS + lo-16 from global blob, merged to exact fp32.
// Chunk layout [c][jg][l=64][rr=4dw] -> lane-stride 16B, conflict-free ds_read_b128.
template <typename F>
__device__ __forceinline__ void lstm_lds(int blk, int tid, int nc, F getx,
                                         const uint32_t* wch0, const uint32_t* lch0,
                                         const float* bih, const float* bhh,
                                         float* hout, float* cst,
                                         float* xs, float* gate_s) {
  const int lane = tid & 63;
  const int bg = (tid >> 6) & 3;
  const int jg = tid >> 8;            // gate index 0..3 (i,f,g,o)
  const int b0 = bg * 8;
  const int hb = blk << 2;
  const int woff = jg * 256 + lane * 4;

  float acc[4][8];
#pragma unroll
  for (int rr = 0; rr < 4; ++rr) {
    float bv = (lane == 0) ? (bih[jg * 1024 + hb + rr] + bhh[jg * 1024 + hb + rr]) : 0.f;
#pragma unroll
    for (int bb = 0; bb < 8; ++bb) acc[rr][bb] = bv;
  }

  const int sb = tid >> 5;            // staging batch row
  const int skq = (tid & 31) * 4;     // staging k within chunk
  f32x4 sreg;
  u32x4 lcur, lnxt;
  {
    XW x0 = getx(0);
    lcur = *(const u32x4*)(lch0 + woff);          // lo-16 chunk 0
    sreg = *(const f32x4*)(x0.x + (size_t)sb * x0.ldx + skq);
    *(f32x4*)(xs + sb * 132 + skq) = sreg;
  }
  __syncthreads();

  for (int c = 0; c < nc; ++c) {
    const bool more = (c + 1 < nc);
    if (more) {
      XW xn = getx(c + 1);
      lnxt = *(const u32x4*)(lch0 + (c + 1) * 1024 + woff);
      sreg = *(const f32x4*)(xn.x + (size_t)sb * xn.ldx + skq);
    }
    u32x4 wv = *(const u32x4*)(wch0 + c * 1024 + woff);
    float we[4], wo[4];
#pragma unroll
    for (int rr = 0; rr < 4; ++rr) {
      uint32_t h = wv[rr], l = lcur[rr];
      we[rr] = __uint_as_float((h << 16) | (l & 0xffffu));          // k even: exact fp32
      wo[rr] = __uint_as_float((h & 0xffff0000u) | (l >> 16));      // k odd:  exact fp32
    }
#pragma unroll
    for (int bb = 0; bb < 8; ++bb) {
      float2 x2 = *(const float2*)(xs + (b0 + bb) * 132 + lane * 2);
#pragma unroll
      for (int rr = 0; rr < 4; ++rr)
        acc[rr][bb] = fmaf(wo[rr], x2.y, fmaf(we[rr], x2.x, acc[rr][bb]));
    }
    __syncthreads();                   // everyone done reading xs
    if (more) {
      *(f32x4*)(xs + sb * 132 + skq) = sreg;   // compiler inserts waitcnt
      lcur = lnxt;
      __syncthreads();
    }
  }

  // reduce 32 partials across 64 lanes: halving butterfly
  float v[32];
#pragma unroll
  for (int rr = 0; rr < 4; ++rr)
#pragma unroll
    for (int bb = 0; bb < 8; ++bb) v[rr * 8 + bb] = acc[rr][bb];
#pragma unroll
  for (int s = 0; s < 5; ++s) {
    const int d = 32 >> s;
    const int half = 32 >> (s + 1);
    const bool up = (lane & d) != 0;
#pragma unroll
    for (int i = 0; i < 16; ++i) {
      if (i < half) {
        float send = up ? v[i] : v[i + half];
        float got = __shfl_xor(send, d);
        v[i] = (up ? v[i + half] : v[i]) + got;
      }
    }
  }
  v[0] += __shfl_xor(v[0], 1);
  if ((lane & 1) == 0) {
    int p = (lane >> 1) & 31;
    int rr = p >> 3, bb = p & 7;
    gate_s[(jg * 4 + rr) * 33 + (b0 + bb)] = v[0];
  }
  __syncthreads();
  if (tid < 128) {
    int hl = tid >> 5, b = tid & 31;
    float gi = gate_s[(0 + hl) * 33 + b];
    float gf = gate_s[(4 + hl) * 33 + b];
    float gg = gate_s[(8 + hl) * 33 + b];
    float go = gate_s[(12 + hl) * 33 + b];
    int idx = b * 1024 + hb + hl;
    float c0v = cst[idx];
    float cn = sigm(gf) * c0v + sigm(gi) * tanhf(gg);
    coh_store1(cst + idx, cn);
    coh_store1(hout + idx, sigm(go) * tanhf(cn));
  }
  __syncthreads();
}

// fused attention for batch b (one block per b); scratch S = 5376 floats
__device__ void stage_attn(int b, int tid, int t, const ScanParams& P,
                           const float* ah_cur, float* ctx_out, float* S) {
  float* ah_l = S;           // 1024 (phase A only)
  float* part = S + 1024;    // 1024 (phase A only)
  float* lf   = S;           // 128*33 = 4224 (conv/energy; overlaps ah_l/part)
  float* sLoc = S + 4224;    // 572
  float* q_s  = S + 4800;    // 128
  float* vw_s = S + 4928;    // 128
  float* red  = S + 5056;    // 8
  float* aw_s = S + 5064;    // 256
  float* cpart= S + 1024;    // 1024 (phase E; lf dead by then)

  float ahv = ah_cur[b * 1024 + tid];
  if (tid < 572) {
    int c = tid / 286, i = tid % 286;
    int src = i - 15;
    float vv = 0.f;
    if (src >= 0 && src < 256) vv = (c == 0 ? P.aw : P.awc)[b * 256 + src];
    sLoc[c * 286 + i] = vv;
  } else if (tid < 700) {
    vw_s[tid - 572] = P.vw[tid - 572];
  }
  ah_l[tid] = ahv;
  __syncthreads();
  // phase A: q partials
  {
    const int js = tid >> 7, a = tid & 127;
    const float* ahb = ah_l + js * 128;
    const float* qp = P.qW + (size_t)(js * 128) * 128 + a;
    float p0 = 0.f, p1 = 0.f, p2 = 0.f, p3 = 0.f;
    for (int j = 0; j < 128; j += 4) {
      p0 += ahb[j] * qp[(size_t)j * 128];
      p1 += ahb[j + 1] * qp[(size_t)(j + 1) * 128];
      p2 += ahb[j + 2] * qp[(size_t)(j + 2) * 128];
      p3 += ahb[j + 3] * qp[(size_t)(j + 3) * 128];
    }
    part[tid] = (p0 + p1) + (p2 + p3);
  }
  __syncthreads();
  if (tid < 128) {
    float q = 0.f;
#pragma unroll
    for (int js = 0; js < 8; ++js) q += part[js * 128 + tid];
    q_s[tid] = q;
  }
  __syncthreads();   // part/ah_l dead; lf region free
  const int len_b = P.lens[b];
#pragma unroll 1
  for (int h = 0; h < 2; ++h) {
    const int tt0 = h << 7;
    {  // location conv for tt in [tt0, tt0+128): thread = f(32) x seg(32), 4 tt each
      const int f = tid >> 5, seg = tid & 31;
      float a0 = 0.f, a1 = 0.f, a2 = 0.f, a3 = 0.f;
      const float* wf = P.locW + f * 62;
#pragma unroll
      for (int c2 = 0; c2 < 2; ++c2)
#pragma unroll
        for (int k = 0; k < 31; ++k) {
          float wv = wf[c2 * 31 + k];
          const float* sl = sLoc + c2 * 286 + tt0 + seg * 4 + k;
          a0 = fmaf(sl[0], wv, a0); a1 = fmaf(sl[1], wv, a1);
          a2 = fmaf(sl[2], wv, a2); a3 = fmaf(sl[3], wv, a3);
        }
      lf[(seg * 4 + 0) * 33 + f] = a0; lf[(seg * 4 + 1) * 33 + f] = a1;
      lf[(seg * 4 + 2) * 33 + f] = a2; lf[(seg * 4 + 3) * 33 + f] = a3;
    }
    __syncthreads();
    {  // energies: thread = ttl(128) x aq(8)
      const int ttl = tid >> 3, aq = tid & 7;
      const int tt = tt0 + ttl;
      const float* pm = P.pmem + (size_t)(b * 256 + tt) * 128;
      const float* lfr = lf + ttl * 33;
      float lfv[32];
#pragma unroll
      for (int f = 0; f < 32; ++f) lfv[f] = lfr[f];
      float ep = 0.f;
#pragma unroll 2
      for (int ai = 0; ai < 16; ++ai) {
        int a = aq * 16 + ai;
        const float4* lt = (const float4*)(P.linT + a * 32);
        float lfa = 0.f;
#pragma unroll
        for (int u = 0; u < 8; ++u) {
          float4 l4 = lt[u];
          lfa += l4.x * lfv[u * 4] + l4.y * lfv[u * 4 + 1] + l4.z * lfv[u * 4 + 2] + l4.w * lfv[u * 4 + 3];
        }
        ep += vw_s[a] * tanhf(q_s[a] + lfa + pm[a]);
      }
      ep += __shfl_xor(ep, 1); ep += __shfl_xor(ep, 2); ep += __shfl_xor(ep, 4);
      if (aq == 0) aw_s[tt] = (tt < len_b) ? ep : -1e9f;
    }
    __syncthreads();
  }
  // softmax over aw_s (in place)
  if (tid < 64) {
    float m0 = fmaxf(fmaxf(aw_s[tid], aw_s[64 + tid]), fmaxf(aw_s[128 + tid], aw_s[192 + tid]));
#pragma unroll
    for (int m = 32; m >= 1; m >>= 1) m0 = fmaxf(m0, __shfl_xor(m0, m));
    if (tid == 0) red[0] = m0;
  }
  __syncthreads();
  const float mx = red[0];
  if (tid < 256) aw_s[tid] = expf(aw_s[tid] - mx);
  __syncthreads();
  if (tid < 64) {
    float s0 = aw_s[tid] + aw_s[64 + tid] + aw_s[128 + tid] + aw_s[192 + tid];
#pragma unroll
    for (int m = 32; m >= 1; m >>= 1) s0 += __shfl_xor(s0, m);
    if (tid == 0) red[1] = s0;
  }
  __syncthreads();
  const float inv = 1.f / red[1];
  if (tid < 256) {
    float awv = aw_s[tid] * inv;
    aw_s[tid] = awv;
    coh_store1(P.aw + b * 256 + tid, awv);
    coh_store1(P.awc + b * 256 + tid, P.awc[b * 256 + tid] + awv);
    coh_store1(P.align_out + (size_t)b * 204800 + (size_t)t * 256 + tid, awv);
  }
  __syncthreads();
  // phase E: ctx = aw @ enc
  {
    const int ee = tid & 511, hf = tid >> 9;
    const float* encb = P.enc + (size_t)b * 131072 + (size_t)hf * 128 * 512 + ee;
    float a0 = 0.f, a1 = 0.f, a2 = 0.f, a3 = 0.f;
    for (int tt = 0; tt < 128; tt += 4) {
      a0 += aw_s[hf * 128 + tt] * encb[(size_t)tt * 512];
      a1 += aw_s[hf * 128 + tt + 1] * encb[(size_t)(tt + 1) * 512];
      a2 += aw_s[hf * 128 + tt + 2] * encb[(size_t)(tt + 2) * 512];
      a3 += aw_s[hf * 128 + tt + 3] * encb[(size_t)(tt + 3) * 512];
    }
    cpart[hf * 512 + ee] = (a0 + a1) + (a2 + a3);
  }
  __syncthreads();
  if (tid < 512) coh_store1(ctx_out + b * 512 + tid, cpart[tid] + cpart[512 + tid]);
}

__device__ void stage_proj(int b, int tid, int tp, const ScanParams& P,
                           const float* dh_prev, const float* ctx_prev, float* S) {
  float* hc    = S;         // 1536
  float* partm = S + 1536;  // 480
  float* partg = S + 2016;  // 32
  for (int i = tid; i < 1536; i += 1024)
    hc[i] = (i < 1024) ? dh_prev[b * 1024 + i] : ctx_prev[b * 512 + (i - 1024)];
  __syncthreads();
  if (tid < 480) {
    int ks = tid / 80, m = tid % 80;
    const float* pWk = P.pW + (size_t)(ks * 256) * 80 + m;
    const float* hck = hc + ks * 256;
    float a0 = 0.f, a1 = 0.f, a2 = 0.f, a3 = 0.f;
    for (int k = 0; k < 256; k += 4) {
      a0 += hck[k] * pWk[(size_t)k * 80];
      a1 += hck[k + 1] * pWk[(size_t)(k + 1) * 80];
      a2 += hck[k + 2] * pWk[(size_t)(k + 2) * 80];
      a3 += hck[k + 3] * pWk[(size_t)(k + 3) * 80];
    }
    partm[ks * 80 + m] = (a0 + a1) + (a2 + a3);
  } else if (tid < 512) {
    int s = tid - 480;
    float acc = 0.f;
    for (int k = s * 48; k < s * 48 + 48; ++k) acc += hc[k] * P.gW[k];
    partg[s] = acc;
  }
  __syncthreads();
  if (tid < 80) {
    float acc = P.pb[tid];
#pragma unroll
    for (int s = 0; s < 6; ++s) acc += partm[s * 80 + tid];
    coh_store1(P.mel_out + b * 64000 + tid * 800 + tp, acc);
  }
  if (tid == 511) {
    float acc = P.gb[0];
#pragma unroll
    for (int s = 0; s < 32; ++s) acc += partg[s];
    coh_store1(P.gate_out + b * 800 + tp, acc);
  }
  __syncthreads();
}

__global__ void __launch_bounds__(1024, 4) scan_kernel(ScanParams P) {
  extern __shared__ char dynsmem[];
  uint32_t* wlds = (uint32_t*)dynsmem;                       // 34816 dwords (hi-16)
  float* scratch = (float*)(dynsmem + 139264);               // 5376 floats
  float* xs = scratch;                                       // 4224
  float* gate_s = scratch + 4224;                            // 528
  const int blk = blockIdx.x, tid = threadIdx.x;

  // ---- prologue: gather this block's weight slice -> LDS hi-16 (truncated) ----
  {
    float* tmp = xs;                                         // 16*128 = 2048 floats
    for (int c = 0; c < WCHUNKS_A + WCHUNKS_D; ++c) {
      const int row16 = tid >> 6;
      const int kk = (tid & 63) * 2;
      const int j = (row16 >> 2) * 1024 + blk * 4 + (row16 & 3);
      float2 wv = *(const float2*)wsrc(c, j, kk, P.aWih, P.aWhh, P.dWih, P.dWhh);
      *(float2*)(tmp + row16 * 128 + kk) = wv;
      __syncthreads();
      const int rr = tid & 3, jgq = (tid >> 2) & 3, l = tid >> 4;
      uint32_t hi0 = __float_as_uint(tmp[(jgq * 4 + rr) * 128 + l * 2]) >> 16;
      uint32_t hi1 = __float_as_uint(tmp[(jgq * 4 + rr) * 128 + l * 2 + 1]) >> 16;
      wlds[c * 1024 + jgq * 256 + l * 4 + rr] = hi0 | (hi1 << 16);
      __syncthreads();
    }
  }
  __syncthreads();

  const uint32_t* lblk = P.wlo + (size_t)blk * WBLK_DW;
  uint32_t* slots = P.bar;
  uint32_t bk = 0;

  for (int i = 0; i <= TDEC; ++i) {
    const int pi = i & 1, pim1 = pi ^ 1;
    // ---- stage X: attn-LSTM(i) then dec-LSTM(i-1) ----
    if (i < TDEC) {
      const float* pre_t = P.pre + (size_t)i * 8192;
      const float* ctx_r = P.ctx + pim1 * 16384;
      const float* ah_r  = P.ah + pim1 * 32768;
      auto getxA = [&](int c) -> XW {
        XW r;
        if (c < 2)      { r.x = pre_t + c * 128;        r.ldx = 256;  }
        else if (c < 6) { r.x = ctx_r + (c - 2) * 128;  r.ldx = 512;  }
        else            { r.x = ah_r + (c - 6) * 128;   r.ldx = 1024; }
        return r;
      };
      lstm_lds(blk, tid, WCHUNKS_A, getxA, wlds, lblk, P.abih, P.abhh,
               P.ah + pi * 32768, P.ac, xs, gate_s);
    }
    if (i >= 1) {
      const float* ah_w  = P.ah + pim1 * 32768;    // ah(i-1)
      const float* ctx_w = P.ctx + pim1 * 16384;   // ctx(i-1)
      const float* dh_r  = P.dh + pi * 32768;      // dh(i-2)
      auto getxD = [&](int c) -> XW {
        XW r;
        if (c < 8)       { r.x = ah_w + c * 128;         r.ldx = 1024; }
        else if (c < 12) { r.x = ctx_w + (c - 8) * 128;  r.ldx = 512;  }
        else             { r.x = dh_r + (c - 12) * 128;  r.ldx = 1024; }
        return r;
      };
      lstm_lds(blk, tid, WCHUNKS_D, getxD, wlds + WCHUNKS_A * 1024,
               lblk + WCHUNKS_A * 1024, P.dbih, P.dbhh,
               P.dh + pim1 * 32768, P.dc, xs, gate_s);
    }
    gbar(slots, ++bk);
    // ---- stage Y: attention(i) || proj(i-1) ----
    if (blk < 32) {
      if (i < TDEC) stage_attn(blk, tid, i, P, P.ah + pi * 32768, P.ctx + pi * 16384, scratch);
    } else if (blk < 64) {
      if (i >= 1) stage_proj(blk - 32, tid, i - 1, P, P.dh + pim1 * 32768, P.ctx + pim1 * 16384, scratch);
    }
    gbar(slots, ++bk);
  }
}

// ---------------- host launch ----------------
extern "C" void kernel_launch(void* const* d_in, const int* in_sizes, int n_in,
                              void* d_out, int out_size, void* d_ws, size_t ws_size,
                              hipStream_t stream) {
  (void)in_sizes; (void)n_in; (void)out_size; (void)ws_size;
  const float* enc   = (const float*)d_in[0];
  const float* decin = (const float*)d_in[1];
  const int*   lens  = (const int*)d_in[2];
  const float* w1    = (const float*)d_in[3];
  const float* w2    = (const float*)d_in[4];
  const float* aWih  = (const float*)d_in[5];
  const float* aWhh  = (const float*)d_in[6];
  const float* abih  = (const float*)d_in[7];
  const float* abhh  = (const float*)d_in[8];
  const float* qW    = (const float*)d_in[9];
  const float* memW  = (const float*)d_in[10];
  const float* vw    = (const float*)d_in[11];
  const float* locW  = (const float*)d_in[12];
  const float* linW  = (const float*)d_in[13];
  const float* dWih  = (const float*)d_in[14];
  const float* dWhh  = (const float*)d_in[15];
  const float* dbih  = (const float*)d_in[16];
  const float* dbhh  = (const float*)d_in[17];
  const float* pW    = (const float*)d_in[18];
  const float* pb    = (const float*)d_in[19];
  const float* gW    = (const float*)d_in[20];
  const float* gb    = (const float*)d_in[21];

  float* ws  = (float*)d_ws;
  float* out = (float*)d_out;

  (void)hipMemsetAsync(ws, 0, (size_t)STATE_FLOATS * sizeof(float), stream);

  uint32_t k1a, k1b, k2a, k2b;
  { uint32_t a = 0u, b = 0u; tf2x32(0u, 42u, a, b); k1a = a; k1b = b; }
  { uint32_t a = 0u, b = 1u; tf2x32(0u, 42u, a, b); k2a = a; k2b = b; }

  transpose_k<<<dim3((256 * 80 + 255) / 256), dim3(256), 0, stream>>>(w1, ws + W1T_OFF, 256, 80);
  transpose_k<<<dim3((256 * 256 + 255) / 256), dim3(256), 0, stream>>>(w2, ws + W2T_OFF, 256, 256);
  transpose_k<<<dim3((32 * 128 + 255) / 256), dim3(256), 0, stream>>>(linW, ws + LINT_OFF, 32, 128);
  prenet1_kernel<<<dim3(800), dim3(256), 0, stream>>>(decin, ws + W1T_OFF, ws + PRE_OFF, k1a, k1b);
  prenet2_kernel<<<dim3(800), dim3(256), 0, stream>>>(ws + W2T_OFF, ws + PRE_OFF, k2a, k2b);
  pmem_kernel<<<dim3(1024), dim3(128), 0, stream>>>(enc, memW, ws + PMEM_OFF);
  mklo_kernel<<<dim3(256), dim3(1024), 0, stream>>>(aWih, aWhh, dWih, dWhh,
                                                    (uint32_t*)(ws + BLOB_OFF));

  ScanParams prm;
  prm.enc = enc; prm.lens = lens;
  prm.aWih = aWih; prm.aWhh = aWhh; prm.abih = abih; prm.abhh = abhh;
  prm.qW = qW; prm.vw = vw; prm.locW = locW; prm.linT = ws + LINT_OFF;
  prm.dWih = dWih; prm.dWhh = dWhh; prm.dbih = dbih; prm.dbhh = dbhh;
  prm.pW = pW; prm.pb = pb; prm.gW = gW; prm.gb = gb;
  prm.ah = ws + AH_OFF; prm.ac = ws + AC_OFF;
  prm.dh = ws + DH_OFF; prm.dc = ws + DC_OFF;
  prm.ctx = ws + CTX_OFF; prm.aw = ws + AW_OFF; prm.awc = ws + AWC_OFF;
  prm.bar = (uint32_t*)(ws + BAR_OFF);
  prm.wlo = (const uint32_t*)(ws + BLOB_OFF);
  prm.pre = ws + PRE_OFF; prm.pmem = ws + PMEM_OFF;
  prm.mel_out = out; prm.gate_out = out + 2048000; prm.align_out = out + 2073600;

  (void)hipFuncSetAttribute((const void*)scan_kernel,
                            hipFuncAttributeMaxDynamicSharedMemorySize, SMEM_BYTES);

  void* kargs[] = { (void*)&prm };
  (void)hipLaunchCooperativeKernel(scan_kernel, dim3(256), dim3(1024), kargs, SMEM_BYTES, stream);
}